// Round 8
// baseline (237.365 us; speedup 1.0000x reference)
//
#include <hip/hip_runtime.h>
#include <hip/hip_cooperative_groups.h>
#include <math.h>

namespace cg = cooperative_groups;

#define HH 256
#define WW 256
#define VV 192
#define DD 256

// geometry (matches reference linspace(-sqrt2,sqrt2,256), DT = 2*sqrt2/256)
#define DSQ2      1.41421356237309504880
#define F_DT      ((float)(2.0 * DSQ2 / 256.0))
#define F_INV_DS  ((float)(255.0 / (2.0 * DSQ2)))        // 90.1562 index per world unit
#define F_SIG     ((float)(256.0 * DSQ2 / 255.0))        // 1.41976 px per index step
#define F_RAD     ((float)(128.0 * DSQ2))                // 181.0193

#define TPITCH 67        // 66 used cols + 1 pad
#define NSEG 16
#define NV (VV / NSEG)   // 12 views per bwd segment

static __device__ __forceinline__ float view_angle(int v) {
    // matches np.linspace(0, pi, 192, endpoint=False): f64 mul then cast
    return (float)((double)v * (3.14159265358979323846 / 192.0));
}

// ---------------------------------------------------------------------------
// One cooperative kernel, three phases separated by grid.sync():
//  P0: sacc = 0, out = input
//  P1: fwd tile-scatter into sacc (unit = tile*192+view, contiguous per block,
//      tile restaged only when it changes)
//  P2: bwd pixel-gather (unit = pixelblock*16+seg, contiguous per block, acc
//      carried in registers across segs), atomicAdd(-w*DT*acc) into out
// ---------------------------------------------------------------------------
__global__ __launch_bounds__(256)
void fused_kernel(const float* __restrict__ input,
                  const float* __restrict__ proj,
                  const float* __restrict__ weight,
                  float* __restrict__ out,
                  float* __restrict__ sacc,
                  int nb)
{
    cg::grid_group grid = cg::this_grid();
    __shared__ float lds[66 * TPITCH];    // P1: image tile | P2: temp segment
    __shared__ float4 s_g[NV];
    const int tid  = threadIdx.x;
    const int lane = tid & 63;
    const int wv   = tid >> 6;
    const int G    = gridDim.x;
    const int bid  = blockIdx.x;

    // ---------------- phase 0 ----------------
    {
        const int nsino4 = nb * VV * (DD / 4);
        float4* s4 = (float4*)sacc;
        for (int i = bid * 256 + tid; i < nsino4; i += G * 256)
            s4[i] = make_float4(0.f, 0.f, 0.f, 0.f);
        const int npix4 = nb * HH * (WW / 4);
        const float4* in4 = (const float4*)input;
        float4* o4 = (float4*)out;
        for (int i = bid * 256 + tid; i < npix4; i += G * 256)
            o4[i] = in4[i];
    }
    grid.sync();

    // ---------------- phase 1: forward ----------------
    {
        const int N1 = nb * 16 * VV;                      // (tile, view) units
        const int u0 = (int)((long long)bid * N1 / G);
        const int u1 = (int)((long long)(bid + 1) * N1 / G);
        int tg_cur = -1;
        int tx = 0, ty = 0, b = 0, lox = 0, loy = 0;
        unsigned spanx = 0, spany = 0;
        float xwl = 0.f, xwh = 0.f, ywl = 0.f, ywh = 0.f;
        for (int u = u0; u < u1; ++u) {
            const int tg = u / VV;                        // b*16 + tile
            const int v  = u - tg * VV;
            if (tg != tg_cur) {
                __syncthreads();                          // protect prior tile reads
                tg_cur = tg;
                b  = tg >> 4;
                tx = (tg & 3) << 6;
                ty = ((tg >> 2) & 3) << 6;
                const float* __restrict__ img = input + (b << 16);
                for (int k = tid; k < 64 * 16; k += 256) {       // interior float4
                    const int r  = k >> 4;
                    const int c4 = (k & 15) << 2;
                    const float4 val = *(const float4*)(img + ((ty + r) << 8) + tx + c4);
                    float* dst = lds + (r + 1) * TPITCH + 1 + c4;
                    dst[0] = val.x; dst[1] = val.y; dst[2] = val.z; dst[3] = val.w;
                }
                if (tid < 132) {                                 // halo cols 0,65
                    const int r  = tid >> 1;
                    const int cc = (tid & 1) ? 65 : 0;
                    const int gx = tx - 1 + cc, gy = ty - 1 + r;
                    float hv = 0.0f;
                    if ((unsigned)gx < 256u && (unsigned)gy < 256u) hv = img[(gy << 8) + gx];
                    lds[r * TPITCH + cc] = hv;
                }
                if (tid < 128) {                                 // halo rows 0,65
                    const int cc = 1 + (tid & 63);
                    const int r  = (tid >> 6) ? 65 : 0;
                    const int gx = tx - 1 + cc, gy = ty - 1 + r;
                    float hv = 0.0f;
                    if ((unsigned)gx < 256u && (unsigned)gy < 256u) hv = img[(gy << 8) + gx];
                    lds[r * TPITCH + cc] = hv;
                }
                lox = (tx == 0) ? -1 : 0;
                loy = (ty == 0) ? -1 : 0;
                spanx = (unsigned)(64 - lox);
                spany = (unsigned)(64 - loy);
                xwl = ((float)(tx + lox) + 0.5f) * (1.0f / 128.0f) - 1.0f;
                xwh = ((float)(tx + 64)  + 0.5f) * (1.0f / 128.0f) - 1.0f;
                ywl = ((float)(ty + loy) + 0.5f) * (1.0f / 128.0f) - 1.0f;
                ywh = ((float)(ty + 64)  + 0.5f) * (1.0f / 128.0f) - 1.0f;
                __syncthreads();
            }

            float sn, cs;
            sincosf(view_angle(v), &sn, &cs);
            const float Xd = -sn * F_SIG, Yd = cs * F_SIG;
            const float Xt =  cs * F_SIG, Yt = sn * F_SIG;
            const float X0 = 127.5f - F_RAD * (cs - sn);
            const float Y0 = 127.5f - F_RAD * (cs + sn);

            const float dA = -xwl * sn, dB = -xwh * sn;
            const float dC =  ywl * cs, dDq =  ywh * cs;
            const float tAq =  xwl * cs, tB =  xwh * cs;
            const float tC =  ywl * sn, tD =  ywh * sn;
            const float dcmin = 127.5f + (fminf(dA, dB) + fminf(dC, dDq)) * F_INV_DS;
            const float dcmax = 127.5f + (fmaxf(dA, dB) + fmaxf(dC, dDq)) * F_INV_DS;
            const float tcmin = 127.5f + (fminf(tAq, tB) + fminf(tC, tD)) * F_INV_DS;
            const float tcmax = 127.5f + (fmaxf(tAq, tB) + fmaxf(tC, tD)) * F_INV_DS;
            const int dlo = max(0, (int)ceilf(dcmin - 0.002f));
            const int dhi = min(255, (int)floorf(dcmax + 0.002f));
            const int tlo = max(0, (int)ceilf(tcmin - 0.002f));
            const int thi = min(255, (int)floorf(tcmax + 0.002f));

            const int sbase = (b * VV + v) << 8;
            for (int dbase = dlo; dbase <= dhi; dbase += 64) {
                const int d = dbase + lane;
                float acc = 0.0f;
                float xc = fmaf((float)d, Xd, fmaf((float)(tlo + wv), Xt, X0)) - (float)tx + 1.0f;
                float yc = fmaf((float)d, Yd, fmaf((float)(tlo + wv), Yt, Y0)) - (float)ty + 1.0f;
                const float step_x = 4.0f * Xt, step_y = 4.0f * Yt;
#pragma unroll 2
                for (int t = tlo + wv; t <= thi; t += 4) {
                    const float xf = floorf(xc);
                    const float yf = floorf(yc);
                    const int cx = (int)xf;
                    const int cy = (int)yf;
                    const float fx = xc - xf;
                    const float fy = yc - yf;
                    const bool ok = (((unsigned)(cx - 1 - lox) < spanx) &
                                     ((unsigned)(cy - 1 - loy) < spany));
                    const int cxc = min(max(cx, 0), 65);
                    const int cyc = min(max(cy, 0), 64);
                    const float* p = lds + cyc * TPITCH + cxc;
                    const float v00 = p[0],      v10 = p[1];
                    const float v01 = p[TPITCH], v11 = p[TPITCH + 1];
                    const float top = fmaf(fx, v10 - v00, v00);
                    const float bot = fmaf(fx, v11 - v01, v01);
                    const float smp = fmaf(fy, bot - top, top);
                    acc += ok ? smp : 0.0f;
                    xc += step_x; yc += step_y;
                }
                if (acc != 0.0f && d <= dhi)
                    atomicAdd(sacc + sbase + d, acc);
            }
        }
    }
    grid.sync();

    // ---------------- phase 2: adjoint + update ----------------
    {
        const int N2 = (nb * HH * WW / 512) * NSEG;       // (pixelblock, seg) units
        const int u0 = (int)((long long)bid * N2 / G);
        const int u1 = (int)((long long)(bid + 1) * N2 / G);
        const float c = -weight[0] * F_DT;
        int pb_cur = -1, idx = 0, b = 0;
        float acc0 = 0.f, acc1 = 0.f, xw = 0.f, yw0 = 0.f, yw1 = 0.f;
        for (int u = u0; u < u1; ++u) {
            const int pb  = u >> 4;
            const int seg = u & 15;
            if (pb != pb_cur) {
                if (pb_cur >= 0) {
                    atomicAdd(out + idx, c * acc0);
                    atomicAdd(out + idx + 256, c * acc1);
                }
                pb_cur = pb;
                acc0 = acc1 = 0.f;
                idx = (pb << 9) + tid;
                b = pb >> 7;
                const int y0 = (idx >> 8) & 255;
                const int x  = idx & 255;
                xw  = (float)x  * (1.0f / 128.0f) + (0.5f / 128.0f - 1.0f);
                yw0 = (float)y0 * (1.0f / 128.0f) + (0.5f / 128.0f - 1.0f);
                yw1 = yw0 + (1.0f / 128.0f);
            }
            __syncthreads();                              // protect prior segment reads
            if (tid < NV) {
                float sn2, cs2;
                sincosf(view_angle(seg * NV + tid), &sn2, &cs2);
                s_g[tid] = make_float4(cs2, sn2, F_SIG * cs2, F_SIG * sn2);
            }
            {   // stage lds = DT*sacc - proj : NV*DD/4 = 768 float4 chunks
                const int base = (b * VV + seg * NV) << 8;
                const float4* s4 = (const float4*)(sacc + base);
                const float4* p4 = (const float4*)(proj + base);
#pragma unroll
                for (int k = 0; k < 3; ++k) {
                    const int i = tid + (k << 8);
                    const float4 a = s4[i];
                    const float4 p = p4[i];
                    ((float4*)lds)[i] = make_float4(
                        fmaf(F_DT, a.x, -p.x), fmaf(F_DT, a.y, -p.y),
                        fmaf(F_DT, a.z, -p.z), fmaf(F_DT, a.w, -p.w));
                }
            }
            __syncthreads();

#pragma unroll 2
            for (int vi = 0; vi < NV; ++vi) {
                const float4 g = s_g[vi];                 // cs, sn, A, B
                const float* __restrict__ row = lds + (vi << 8);
#pragma unroll
                for (int p = 0; p < 2; ++p) {
                    const float yw = p ? yw1 : yw0;
                    const float sw = fmaf(-xw, g.y, yw * g.x);
                    const float tw = fmaf( xw, g.x, yw * g.y);
                    const float dc = fmaf(sw, F_INV_DS, 127.5f);
                    const float tc = fmaf(tw, F_INV_DS, 127.5f);
                    const float d0f = floorf(dc);
                    const float t0f = floorf(tc);
                    const int d0 = (int)d0f;
                    const float fd = dc - d0f;
                    const float ft = tc - t0f;

                    const float dx00 = fmaf(g.z, -ft, g.w * fd);
                    const float dyn  = fmaf(g.z,  fd, g.w * ft);
                    const float dx01 = dx00 + g.z;
                    const float dy01 = g.w - dyn;
                    const float dx10 = dx00 - g.w;
                    const float dy10 = g.z - dyn;
                    const float dx11 = dx01 - g.w;
                    const float dy11 = dy10 + g.w;

                    const float w00 = fmaxf(0.0f, 1.0f - fabsf(dx00)) * fmaxf(0.0f, 1.0f - fabsf(dyn));
                    const float w01 = fmaxf(0.0f, 1.0f - fabsf(dx01)) * fmaxf(0.0f, 1.0f - fabsf(dy01));
                    const float w10 = fmaxf(0.0f, 1.0f - fabsf(dx10)) * fmaxf(0.0f, 1.0f - fabsf(dy10));
                    const float w11 = fmaxf(0.0f, 1.0f - fabsf(dx11)) * fmaxf(0.0f, 1.0f - fabsf(dy11));

                    const float rA = row[d0];
                    const float rB = row[d0 + 1];
                    if (p == 0) {
                        acc0 = fmaf(w00 + w01, rA, acc0);
                        acc0 = fmaf(w10 + w11, rB, acc0);
                    } else {
                        acc1 = fmaf(w00 + w01, rA, acc1);
                        acc1 = fmaf(w10 + w11, rB, acc1);
                    }
                }
            }
        }
        if (pb_cur >= 0) {
            atomicAdd(out + idx, c * acc0);
            atomicAdd(out + idx + 256, c * acc1);
        }
    }
}

extern "C" void kernel_launch(void* const* d_in, const int* in_sizes, int n_in,
                              void* d_out, int out_size, void* d_ws, size_t ws_size,
                              hipStream_t stream) {
    const float* input  = (const float*)d_in[0];   // [nb, H, W]
    const float* proj   = (const float*)d_in[1];   // [nb, V, D]
    const float* weight = (const float*)d_in[2];   // [1]
    float* out  = (float*)d_out;                   // [nb, H, W]
    float* sacc = (float*)d_ws;                    // [nb, V, D]
    int nb = in_sizes[0] / (HH * WW);              // B*C = 2

    int blocksPerCU = 0;
    (void)hipOccupancyMaxActiveBlocksPerMultiprocessor(&blocksPerCU, fused_kernel, 256, 0);
    if (blocksPerCU < 1) blocksPerCU = 1;
    if (blocksPerCU > 8) blocksPerCU = 8;          // 32-wave/CU cap
    int G = blocksPerCU * 256;                     // 256 CUs on MI355X
    if (G > 2048) G = 2048;

    void* args[] = { (void*)&input, (void*)&proj, (void*)&weight,
                     (void*)&out, (void*)&sacc, (void*)&nb };
    (void)hipLaunchCooperativeKernel(fused_kernel, dim3(G), dim3(256), args, 0, stream);
}

// Round 9
// 101.836 us; speedup vs baseline: 2.3309x; 2.3309x over previous
//
#include <hip/hip_runtime.h>
#include <math.h>

#define HH 256
#define WW 256
#define VV 192
#define DD 256

// geometry (matches reference linspace(-sqrt2,sqrt2,256), DT = 2*sqrt2/256)
#define DSQ2      1.41421356237309504880
#define F_DT      ((float)(2.0 * DSQ2 / 256.0))
#define F_INV_DS  ((float)(255.0 / (2.0 * DSQ2)))        // 90.1562 index per world unit
#define F_SIG     ((float)(256.0 * DSQ2 / 255.0))        // 1.41976 px per index step
#define F_RAD     ((float)(128.0 * DSQ2))                // 181.0193

#define TPITCH 67        // 66 used cols + 1 pad
#define NSEG 16
#define NV (VV / NSEG)   // 12 views per bwd segment -> 12.3 KB LDS -> 8 blocks/CU

static __device__ __forceinline__ float view_angle(int v) {
    // matches np.linspace(0, pi, 192, endpoint=False): f64 mul then cast
    return (float)((double)v * (3.14159265358979323846 / 192.0));
}

// ---------------------------------------------------------------------------
// Kernel 0: out = input ; sacc = 0   (replaces hipMemsetAsync + combine's read)
// ---------------------------------------------------------------------------
__global__ __launch_bounds__(256)
void init_kernel(const float* __restrict__ input,
                 float* __restrict__ out,
                 float* __restrict__ sacc,
                 int npix4, int nsino4) {
    const int stride = gridDim.x * 256;
    const float4* in4 = (const float4*)input;
    float4* o4 = (float4*)out;
    float4* s4 = (float4*)sacc;
    for (int i = blockIdx.x * 256 + threadIdx.x; i < npix4; i += stride)
        o4[i] = in4[i];
    for (int i = blockIdx.x * 256 + threadIdx.x; i < nsino4; i += stride)
        s4[i] = make_float4(0.f, 0.f, 0.f, 0.f);
}

// ---------------------------------------------------------------------------
// Kernel 1: tile-local sample-driven forward projection (round-6 verbatim).
// Block = (64x64 image tile, view, image). lane <-> d, waves <-> t phase.
// Tile + 1-px halo staged in LDS; branchless inner loop; per-thread guarded
// global atomicAdd epilogue.
// ---------------------------------------------------------------------------
__global__ __launch_bounds__(256)
void fwd_tile_kernel(const float* __restrict__ img_all,
                     float* __restrict__ sacc) {
    __shared__ float tile[66 * TPITCH];
    const int tx = (blockIdx.x & 3) << 6;
    const int ty = (blockIdx.x >> 2) << 6;
    const int v  = blockIdx.y;
    const int b  = blockIdx.z;
    const int tid  = threadIdx.x;
    const int lane = tid & 63;
    const int wv   = tid >> 6;

    const float* __restrict__ img = img_all + (b << 16);

    // ---- stage 66x66 (global x,y in [tx-1, tx+64] x [ty-1, ty+64], 0 outside) ----
    for (int k = tid; k < 64 * 16; k += 256) {           // interior, float4
        const int r  = k >> 4;                           // 0..63 -> y = ty+r
        const int c4 = (k & 15) << 2;                    // 0..60 -> x = tx+c4
        const float4 val = *(const float4*)(img + ((ty + r) << 8) + tx + c4);
        float* dst = tile + (r + 1) * TPITCH + 1 + c4;
        dst[0] = val.x; dst[1] = val.y; dst[2] = val.z; dst[3] = val.w;
    }
    if (tid < 132) {                                     // vertical halo cols (0, 65)
        const int r  = tid >> 1;                         // 0..65
        const int cc = (tid & 1) ? 65 : 0;
        const int gx = tx - 1 + cc;
        const int gy = ty - 1 + r;
        float vv = 0.0f;
        if ((unsigned)gx < 256u && (unsigned)gy < 256u) vv = img[(gy << 8) + gx];
        tile[r * TPITCH + cc] = vv;
    }
    if (tid < 128) {                                     // horizontal halo rows (0, 65)
        const int cc = 1 + (tid & 63);
        const int r  = (tid >> 6) ? 65 : 0;
        const int gx = tx - 1 + cc;
        const int gy = ty - 1 + r;
        float vv = 0.0f;
        if ((unsigned)gx < 256u && (unsigned)gy < 256u) vv = img[(gy << 8) + gx];
        tile[r * TPITCH + cc] = vv;
    }

    // ---- geometry: pixel(d,t) = (X0 + d*Xd + t*Xt, Y0 + d*Yd + t*Yt) ----
    float sn, cs;
    sincosf(view_angle(v), &sn, &cs);
    const float Xd = -sn * F_SIG, Yd = cs * F_SIG;
    const float Xt =  cs * F_SIG, Yt = sn * F_SIG;
    const float X0 = 127.5f - F_RAD * (cs - sn);
    const float Y0 = 127.5f - F_RAD * (cs + sn);

    // ownership: ix0 in [tx+lox, tx+63] (edge tiles also own the -1 fringe)
    const int lox = (tx == 0) ? -1 : 0;
    const int loy = (ty == 0) ? -1 : 0;
    const unsigned spanx = (unsigned)(64 - lox);
    const unsigned spany = (unsigned)(64 - loy);

    // (d,t) bbox of owned pixel box via the inverse (orthogonal) map
    const float xwl = ((float)(tx + lox) + 0.5f) * (1.0f / 128.0f) - 1.0f;
    const float xwh = ((float)(tx + 64)  + 0.5f) * (1.0f / 128.0f) - 1.0f;
    const float ywl = ((float)(ty + loy) + 0.5f) * (1.0f / 128.0f) - 1.0f;
    const float ywh = ((float)(ty + 64)  + 0.5f) * (1.0f / 128.0f) - 1.0f;
    const float dA = -xwl * sn, dB = -xwh * sn;
    const float dC =  ywl * cs, dDq =  ywh * cs;
    const float tAq =  xwl * cs, tB =  xwh * cs;
    const float tC =  ywl * sn, tD =  ywh * sn;
    const float dcmin = 127.5f + (fminf(dA, dB) + fminf(dC, dDq)) * F_INV_DS;
    const float dcmax = 127.5f + (fmaxf(dA, dB) + fmaxf(dC, dDq)) * F_INV_DS;
    const float tcmin = 127.5f + (fminf(tAq, tB) + fminf(tC, tD)) * F_INV_DS;
    const float tcmax = 127.5f + (fmaxf(tAq, tB) + fmaxf(tC, tD)) * F_INV_DS;
    const int dlo = max(0, (int)ceilf(dcmin - 0.002f));
    const int dhi = min(255, (int)floorf(dcmax + 0.002f));
    const int tlo = max(0, (int)ceilf(tcmin - 0.002f));
    const int thi = min(255, (int)floorf(tcmax + 0.002f));

    __syncthreads();

    const int sbase = (b * VV + v) << 8;
    for (int dbase = dlo; dbase <= dhi; dbase += 64) {   // 1 iter except rare edge tiles
        const int d = dbase + lane;
        float acc = 0.0f;
        // tile-local coords shifted so floor(xc) == LDS col directly
        float xc = fmaf((float)d, Xd, fmaf((float)(tlo + wv), Xt, X0)) - (float)tx + 1.0f;
        float yc = fmaf((float)d, Yd, fmaf((float)(tlo + wv), Yt, Y0)) - (float)ty + 1.0f;
        const float step_x = 4.0f * Xt, step_y = 4.0f * Yt;
#pragma unroll 2
        for (int t = tlo + wv; t <= thi; t += 4) {
            const float xf = floorf(xc);
            const float yf = floorf(yc);
            const int cx = (int)xf;
            const int cy = (int)yf;
            const float fx = xc - xf;
            const float fy = yc - yf;
            const bool ok = (((unsigned)(cx - 1 - lox) < spanx) &
                             ((unsigned)(cy - 1 - loy) < spany));
            const int cxc = min(max(cx, 0), 65);
            const int cyc = min(max(cy, 0), 64);         // +TPITCH row stays <= 65
            const float* p = tile + cyc * TPITCH + cxc;
            const float v00 = p[0],      v10 = p[1];
            const float v01 = p[TPITCH], v11 = p[TPITCH + 1];
            const float top = fmaf(fx, v10 - v00, v00);
            const float bot = fmaf(fx, v11 - v01, v01);
            const float smp = fmaf(fy, bot - top, top);
            acc += ok ? smp : 0.0f;
            xc += step_x; yc += step_y;
        }
        if (acc != 0.0f && d <= dhi)
            atomicAdd(sacc + sbase + d, acc);
    }
}

// ---------------------------------------------------------------------------
// Kernel 2: pixel-driven exact adjoint (round-6 core), weight folded in,
// atomicAdd directly into out (pre-initialized to input). ir buffer and
// combine kernel eliminated. No bounds checks (dc in [0.5,254.5]).
// ---------------------------------------------------------------------------
__global__ __launch_bounds__(256, 8)
void bwd_partial_kernel(const float* __restrict__ sacc,
                        const float* __restrict__ proj,
                        const float* __restrict__ weight,
                        float* __restrict__ out) {
    __shared__ float s_t[NV * DD];
    __shared__ float4 s_g[NV];
    const int tid = threadIdx.x;
    const int v0 = blockIdx.y * NV;
    const int b  = (int)blockIdx.x >> 7;          // 128 blocks (512 px) per image

    if (tid < NV) {
        float sn, cs;
        sincosf(view_angle(v0 + tid), &sn, &cs);
        s_g[tid] = make_float4(cs, sn, F_SIG * cs, F_SIG * sn);
    }
    {   // stage s_t = DT*sacc - proj : NV*DD/4 = 768 float4 chunks
        const int base = (b * VV + v0) << 8;
        const float4* s4 = (const float4*)(sacc + base);
        const float4* p4 = (const float4*)(proj + base);
#pragma unroll
        for (int k = 0; k < NV * (DD / 4) / 256; ++k) {
            const int i = tid + (k << 8);
            const float4 a = s4[i];
            const float4 p = p4[i];
            float4 r;
            r.x = fmaf(F_DT, a.x, -p.x);
            r.y = fmaf(F_DT, a.y, -p.y);
            r.z = fmaf(F_DT, a.z, -p.z);
            r.w = fmaf(F_DT, a.w, -p.w);
            ((float4*)s_t)[i] = r;
        }
    }
    __syncthreads();

    const int idx = ((int)blockIdx.x << 9) + tid;     // pixel 0; pixel 1 = idx+256
    const int y0 = (idx >> 8) & 255;
    const int x  = idx & 255;
    const float xw  = (float)x  * (1.0f / 128.0f) + (0.5f / 128.0f - 1.0f);
    const float yw0 = (float)y0 * (1.0f / 128.0f) + (0.5f / 128.0f - 1.0f);
    const float yw1 = yw0 + (1.0f / 128.0f);

    float acc0 = 0.0f, acc1 = 0.0f;
#pragma unroll 2
    for (int vi = 0; vi < NV; ++vi) {
        const float4 g = s_g[vi];                 // cs, sn, A=sig*cs, B=sig*sn
        const float* __restrict__ row = s_t + (vi << 8);
#pragma unroll
        for (int p = 0; p < 2; ++p) {
            const float yw = p ? yw1 : yw0;
            const float sw = fmaf(-xw, g.y, yw * g.x);
            const float tw = fmaf( xw, g.x, yw * g.y);
            const float dc = fmaf(sw, F_INV_DS, 127.5f);
            const float tc = fmaf(tw, F_INV_DS, 127.5f);
            const float d0f = floorf(dc);
            const float t0f = floorf(tc);
            const int d0 = (int)d0f;
            const float fd = dc - d0f;
            const float ft = tc - t0f;

            const float dx00 = fmaf(g.z, -ft, g.w * fd);
            const float dyn  = fmaf(g.z,  fd, g.w * ft);
            const float dx01 = dx00 + g.z;
            const float dy01 = g.w - dyn;
            const float dx10 = dx00 - g.w;
            const float dy10 = g.z - dyn;
            const float dx11 = dx01 - g.w;
            const float dy11 = dy10 + g.w;

            const float w00 = fmaxf(0.0f, 1.0f - fabsf(dx00)) * fmaxf(0.0f, 1.0f - fabsf(dyn));
            const float w01 = fmaxf(0.0f, 1.0f - fabsf(dx01)) * fmaxf(0.0f, 1.0f - fabsf(dy01));
            const float w10 = fmaxf(0.0f, 1.0f - fabsf(dx10)) * fmaxf(0.0f, 1.0f - fabsf(dy10));
            const float w11 = fmaxf(0.0f, 1.0f - fabsf(dx11)) * fmaxf(0.0f, 1.0f - fabsf(dy11));

            const float rA = row[d0];
            const float rB = row[d0 + 1];
            if (p == 0) {
                acc0 = fmaf(w00 + w01, rA, acc0);
                acc0 = fmaf(w10 + w11, rB, acc0);
            } else {
                acc1 = fmaf(w00 + w01, rA, acc1);
                acc1 = fmaf(w10 + w11, rB, acc1);
            }
        }
    }

    const float c = -weight[0] * F_DT;
    atomicAdd(out + idx, c * acc0);
    atomicAdd(out + idx + 256, c * acc1);
}

extern "C" void kernel_launch(void* const* d_in, const int* in_sizes, int n_in,
                              void* d_out, int out_size, void* d_ws, size_t ws_size,
                              hipStream_t stream) {
    const float* input  = (const float*)d_in[0];   // [nb, H, W]
    const float* proj   = (const float*)d_in[1];   // [nb, V, D]
    const float* weight = (const float*)d_in[2];   // [1]
    float* out  = (float*)d_out;                   // [nb, H, W]
    float* sacc = (float*)d_ws;                    // [nb, V, D] forward accumulator

    const int nb = in_sizes[0] / (HH * WW);        // B*C = 2
    const int npix = nb * HH * WW;

    init_kernel<<<256, 256, 0, stream>>>(input, out, sacc,
                                         npix / 4, nb * VV * DD / 4);
    fwd_tile_kernel<<<dim3(16, VV, nb), 256, 0, stream>>>(input, sacc);
    bwd_partial_kernel<<<dim3(npix / 512, NSEG), 256, 0, stream>>>(sacc, proj, weight, out);
}